// Round 5
// baseline (557.449 us; speedup 1.0000x reference)
//
#include <hip/hip_runtime.h>

#define NN 100000
#define NE 1600000

typedef __bf16 bf16x8 __attribute__((ext_vector_type(8)));
typedef float f32x4 __attribute__((ext_vector_type(4)));

static __device__ __forceinline__ float bf2f_lo(unsigned int u) {
  return __uint_as_float(u << 16);
}
static __device__ __forceinline__ float bf2f_hi(unsigned int u) {
  return __uint_as_float(u & 0xffff0000u);
}
static __device__ __forceinline__ unsigned short f2bf(float f) {
  unsigned int u = __float_as_uint(f);
  unsigned int r = (u + 0x7fff + ((u >> 16) & 1)) >> 16;  // RNE
  return (unsigned short)r;
}

// ---------------- windowed degree accumulation ----------------
// only counts nodes inside [w0,w1): keeps the counter window L2-resident
__global__ __launch_bounds__(256) void degcnt_win_kernel(
    const int* __restrict__ src, const int* __restrict__ dst,
    int* __restrict__ degO, int* __restrict__ degI, int nE, int w0, int w1) {
  int i = blockIdx.x * blockDim.x + threadIdx.x;
  int stride = gridDim.x * blockDim.x;
  for (int e = i; e < nE; e += stride) {
    int s = src[e];
    int d = dst[e];
    if (s >= w0 && s < w1) atomicAdd(&degO[s], 1);
    if (d >= w0 && d < w1) atomicAdd(&degI[d], 1);
  }
}

__global__ __launch_bounds__(256) void normi_kernel(
    const int* __restrict__ degO, const int* __restrict__ degI,
    float* __restrict__ ns, float* __restrict__ nd, int n) {
  int i = blockIdx.x * blockDim.x + threadIdx.x;
  if (i < n) {
    ns[i] = rsqrtf(fmaxf((float)degO[i], 1.0f));
    nd[i] = rsqrtf(fmaxf((float)degI[i], 1.0f));
  }
}

// ---------------- prefix scan ----------------
__global__ __launch_bounds__(1024) void scan1_kernel(
    const int* __restrict__ deg, int* __restrict__ excl,
    int* __restrict__ blk, int n) {
  __shared__ int lds[1024];
  const int tid = threadIdx.x;
  const int gid = blockIdx.x * 1024 + tid;
  int v = (gid < n) ? deg[gid] : 0;
  lds[tid] = v;
  __syncthreads();
  for (int off = 1; off < 1024; off <<= 1) {
    int t = (tid >= off) ? lds[tid - off] : 0;
    __syncthreads();
    lds[tid] += t;
    __syncthreads();
  }
  if (gid < n) excl[gid] = lds[tid] - v;
  if (tid == 1023) blk[blockIdx.x] = lds[1023];
}

__global__ __launch_bounds__(128) void scan2_kernel(int* __restrict__ blk, int nblk) {
  __shared__ int lds[128];
  const int tid = threadIdx.x;
  int v = (tid < nblk) ? blk[tid] : 0;
  lds[tid] = v;
  __syncthreads();
  for (int off = 1; off < 128; off <<= 1) {
    int t = (tid >= off) ? lds[tid - off] : 0;
    __syncthreads();
    lds[tid] += t;
    __syncthreads();
  }
  if (tid < nblk) blk[tid] = lds[tid] - v;
}

__global__ __launch_bounds__(1024) void scan3_kernel(
    int* __restrict__ row_off, const int* __restrict__ blk,
    int* __restrict__ cursor, int n, int nE) {
  int gid = blockIdx.x * 1024 + threadIdx.x;
  if (gid < n) {
    int v = row_off[gid] + blk[gid >> 10];
    row_off[gid] = v;
    cursor[gid] = v;
  }
  if (gid == 0) row_off[n] = nE;
}

// ---------------- dst-windowed CSR scatter ----------------
__global__ __launch_bounds__(256) void scatter_win_kernel(
    const int* __restrict__ src, const int* __restrict__ dst,
    int* __restrict__ cursor, int* __restrict__ col, int nE, int w0, int w1) {
  int i = blockIdx.x * blockDim.x + threadIdx.x;
  int stride = gridDim.x * blockDim.x;
  for (int e = i; e < nE; e += stride) {
    int d = dst[e];
    if (d >= w0 && d < w1) {
      int pos = atomicAdd(&cursor[d], 1);
      col[pos] = src[e];
    }
  }
}

// ---------------- all weights transpose+convert in one launch ----------------
// Wt[c][k] = bf16(W[k][c]); sizes: W1 128x128, W2 128x128, W3 128x256, W4 256x64
__global__ __launch_bounds__(256) void wconv_all_kernel(
    const float* __restrict__ W1, unsigned short* __restrict__ Wt1,
    const float* __restrict__ W2, unsigned short* __restrict__ Wt2,
    const float* __restrict__ W3, unsigned short* __restrict__ Wt3,
    const float* __restrict__ W4, unsigned short* __restrict__ Wt4) {
  int gid = blockIdx.x * blockDim.x + threadIdx.x;
  const float* W;
  unsigned short* Wt;
  int K, C, i;
  if (gid < 16384) { W = W1; Wt = Wt1; K = 128; C = 128; i = gid; }
  else if (gid < 32768) { W = W2; Wt = Wt2; K = 128; C = 128; i = gid - 16384; }
  else if (gid < 65536) { W = W3; Wt = Wt3; K = 128; C = 256; i = gid - 32768; }
  else if (gid < 81920) { W = W4; Wt = Wt4; K = 256; C = 64; i = gid - 65536; }
  else return;
  int c = i % C, k = i / C;
  Wt[(size_t)c * K + k] = f2bf(W[i]);
}

// ---------------- prescale: out = bf16(feat * ns[row]) ----------------
__global__ __launch_bounds__(256) void prescale_kernel(
    const float* __restrict__ feat, const float* __restrict__ ns,
    unsigned short* __restrict__ out) {
  int idx = blockIdx.x * blockDim.x + threadIdx.x;  // one per 8 elems
  if (idx >= NN * 16) return;
  int row = idx >> 4;
  int c8 = (idx & 15) * 8;
  float sc = ns[row];
  float4 v0 = *reinterpret_cast<const float4*>(feat + (size_t)row * 128 + c8);
  float4 v1 = *reinterpret_cast<const float4*>(feat + (size_t)row * 128 + c8 + 4);
  union { unsigned short u[8]; uint4 v; } p;
  p.u[0] = f2bf(v0.x * sc); p.u[1] = f2bf(v0.y * sc);
  p.u[2] = f2bf(v0.z * sc); p.u[3] = f2bf(v0.w * sc);
  p.u[4] = f2bf(v1.x * sc); p.u[5] = f2bf(v1.y * sc);
  p.u[6] = f2bf(v1.z * sc); p.u[7] = f2bf(v1.w * sc);
  *reinterpret_cast<uint4*>(out + (size_t)row * 128 + c8) = p.v;
}

// ---------------- CSR gather: out[d] = bf16(nd[d] * sum x[s]) ----------------
// one wave per dst node; 8 edges in flight via 8-lane groups, 2x16B loads/lane
__global__ __launch_bounds__(256) void agg_bf16_kernel(
    const unsigned short* __restrict__ x, const int* __restrict__ col,
    const int* __restrict__ row_off, const float* __restrict__ nd,
    unsigned short* __restrict__ out, int nN) {
  const int wid = (blockIdx.x * blockDim.x + threadIdx.x) >> 6;
  const int lane = threadIdx.x & 63;
  if (wid >= nN) return;
  const int beg = row_off[wid];
  const int end = row_off[wid + 1];
  const int g = lane >> 3;    // edge subgroup 0..7
  const int lg = lane & 7;    // 32B chunk within row

  float acc[16] = {};
  for (int i0 = beg; i0 < end; i0 += 64) {
    const int cnt = min(64, end - i0);
    int myc = (lane < cnt) ? col[i0 + lane] : 0;
    for (int j = 0; j < cnt; j += 8) {
      int idx = j + g;
      int s = __shfl(myc, idx);
      float m = (idx < cnt) ? 1.0f : 0.0f;
      const uint4* p = reinterpret_cast<const uint4*>(x + (size_t)s * 128 + lg * 16);
      uint4 v0 = p[0];
      uint4 v1 = p[1];
      acc[0] = fmaf(m, bf2f_lo(v0.x), acc[0]);
      acc[1] = fmaf(m, bf2f_hi(v0.x), acc[1]);
      acc[2] = fmaf(m, bf2f_lo(v0.y), acc[2]);
      acc[3] = fmaf(m, bf2f_hi(v0.y), acc[3]);
      acc[4] = fmaf(m, bf2f_lo(v0.z), acc[4]);
      acc[5] = fmaf(m, bf2f_hi(v0.z), acc[5]);
      acc[6] = fmaf(m, bf2f_lo(v0.w), acc[6]);
      acc[7] = fmaf(m, bf2f_hi(v0.w), acc[7]);
      acc[8] = fmaf(m, bf2f_lo(v1.x), acc[8]);
      acc[9] = fmaf(m, bf2f_hi(v1.x), acc[9]);
      acc[10] = fmaf(m, bf2f_lo(v1.y), acc[10]);
      acc[11] = fmaf(m, bf2f_hi(v1.y), acc[11]);
      acc[12] = fmaf(m, bf2f_lo(v1.z), acc[12]);
      acc[13] = fmaf(m, bf2f_hi(v1.z), acc[13]);
      acc[14] = fmaf(m, bf2f_lo(v1.w), acc[14]);
      acc[15] = fmaf(m, bf2f_hi(v1.w), acc[15]);
    }
  }
  // merge the 8 edge subgroups (lanes differing in bits 3,4,5)
#pragma unroll
  for (int k = 0; k < 16; ++k) {
    acc[k] += __shfl_xor(acc[k], 8);
    acc[k] += __shfl_xor(acc[k], 16);
    acc[k] += __shfl_xor(acc[k], 32);
  }
  if (g == 0) {
    float sc = nd[wid];
    union { unsigned short u[16]; uint4 v[2]; } p;
#pragma unroll
    for (int k = 0; k < 16; ++k) p.u[k] = f2bf(acc[k] * sc);
    uint4* o = reinterpret_cast<uint4*>(out + (size_t)wid * 128 + lg * 16);
    o[0] = p.v[0];
    o[1] = p.v[1];
  }
}

// ---------------- MFMA GEMM: C = bf16((A @ W + b) * postscale) ----------------
template <int K, int COLS>
__global__ __launch_bounds__(256) void gemm_mfma_kernel(
    const unsigned short* __restrict__ A, const unsigned short* __restrict__ Wt,
    const float* __restrict__ bias, const float* __restrict__ postscale,
    unsigned short* __restrict__ C, int nrows) {
  constexpr int TM = 64;
  constexpr int NT = COLS / 16;
  constexpr int KS = K / 32;
  __shared__ unsigned short a_lds[TM * K];
  const int row0 = blockIdx.x * TM;
  const int tid = threadIdx.x;
  const int wave = tid >> 6, lane = tid & 63;

  constexpr int CHUNKS = TM * K * 2 / 16;
  for (int i = tid; i < CHUNKS; i += 256) {
    int byte_lin = i * 16;
    int r = byte_lin / (K * 2);
    int swz = byte_lin ^ ((r & 7) << 4);
    uint4 v = {0u, 0u, 0u, 0u};
    int gr = row0 + r;
    if (gr < nrows)
      v = *reinterpret_cast<const uint4*>(A + (size_t)gr * K + (byte_lin % (K * 2)) / 2);
    *reinterpret_cast<uint4*>((char*)a_lds + swz) = v;
  }
  __syncthreads();

  const int rrow = wave * 16 + (lane & 15);
  const int kofs = (lane >> 4) * 8;
  f32x4 acc[NT];
#pragma unroll
  for (int nt = 0; nt < NT; ++nt) acc[nt] = f32x4{0.f, 0.f, 0.f, 0.f};

  for (int ks = 0; ks < KS; ++ks) {
    const int k0 = ks * 32;
    int abyte = ((rrow * K + k0 + kofs) * 2) ^ ((rrow & 7) << 4);
    bf16x8 a = *reinterpret_cast<const bf16x8*>((const char*)a_lds + abyte);
#pragma unroll
    for (int nt = 0; nt < NT; ++nt) {
      int c = nt * 16 + (lane & 15);
      bf16x8 b = *reinterpret_cast<const bf16x8*>(Wt + (size_t)c * K + k0 + kofs);
      acc[nt] = __builtin_amdgcn_mfma_f32_16x16x32_bf16(a, b, acc[nt], 0, 0, 0);
    }
  }

  __syncthreads();
#pragma unroll
  for (int nt = 0; nt < NT; ++nt) {
    int c = nt * 16 + (lane & 15);
    float bv = bias[c];
#pragma unroll
    for (int r = 0; r < 4; ++r) {
      int lrow = wave * 16 + (lane >> 4) * 4 + r;
      int grow = row0 + lrow;
      float ps = (postscale != nullptr && grow < nrows) ? postscale[grow] : 1.0f;
      float v = (acc[nt][r] + bv) * ps;
      a_lds[lrow * COLS + c] = f2bf(v);
    }
  }
  __syncthreads();
  constexpr int OCH = TM * COLS * 2 / 16;
  for (int i = tid; i < OCH; i += 256) {
    int byte_lin = i * 16;
    int r = byte_lin / (COLS * 2);
    int gr = row0 + r;
    if (gr < nrows)
      *reinterpret_cast<uint4*>(C + (size_t)gr * COLS + (byte_lin % (COLS * 2)) / 2) =
          *reinterpret_cast<const uint4*>((const char*)a_lds + byte_lin);
  }
}

// ---------------- fused MLP + proj (MFMA) ----------------
__global__ __launch_bounds__(256) void mlp_mfma_kernel(
    const unsigned short* __restrict__ H, const unsigned short* __restrict__ Wt3,
    const float* __restrict__ b3, const unsigned short* __restrict__ Wt4,
    const float* __restrict__ b4, float* __restrict__ Out, int nrows) {
  constexpr int TM = 64;
  __shared__ unsigned short h_lds[TM * 128];
  __shared__ unsigned short z_lds[TM * 256];
  const int row0 = blockIdx.x * TM;
  const int tid = threadIdx.x;
  const int wave = tid >> 6, lane = tid & 63;
  const int l15 = lane & 15;
  const int kofs = (lane >> 4) * 8;

  for (int i = tid; i < TM * 128 * 2 / 16; i += 256) {
    int byte_lin = i * 16;
    int r = byte_lin / 256;
    int swz = byte_lin ^ ((r & 7) << 4);
    uint4 v = {0u, 0u, 0u, 0u};
    int gr = row0 + r;
    if (gr < nrows)
      v = *reinterpret_cast<const uint4*>(H + (size_t)gr * 128 + (byte_lin % 256) / 2);
    *reinterpret_cast<uint4*>((char*)h_lds + swz) = v;
  }
  __syncthreads();

  const int rrow = wave * 16 + l15;
  {
    f32x4 acc[16];
#pragma unroll
    for (int nt = 0; nt < 16; ++nt) acc[nt] = f32x4{0.f, 0.f, 0.f, 0.f};
    for (int ks = 0; ks < 4; ++ks) {
      const int k0 = ks * 32;
      int abyte = ((rrow * 128 + k0 + kofs) * 2) ^ ((rrow & 7) << 4);
      bf16x8 a = *reinterpret_cast<const bf16x8*>((const char*)h_lds + abyte);
#pragma unroll
      for (int nt = 0; nt < 16; ++nt) {
        int c = nt * 16 + l15;
        bf16x8 b = *reinterpret_cast<const bf16x8*>(Wt3 + (size_t)c * 128 + k0 + kofs);
        acc[nt] = __builtin_amdgcn_mfma_f32_16x16x32_bf16(a, b, acc[nt], 0, 0, 0);
      }
    }
#pragma unroll
    for (int nt = 0; nt < 16; ++nt) {
      int c = nt * 16 + l15;
      float bv = b3[c];
#pragma unroll
      for (int r = 0; r < 4; ++r) {
        int lrow = wave * 16 + (lane >> 4) * 4 + r;
        float v = fmaxf(acc[nt][r] + bv, 0.0f);
        int zb = (lrow * 512 + c * 2) ^ ((lrow & 7) << 4);
        *reinterpret_cast<unsigned short*>((char*)z_lds + zb) = f2bf(v);
      }
    }
  }
  __syncthreads();

  f32x4 acc2[4];
#pragma unroll
  for (int nt = 0; nt < 4; ++nt) acc2[nt] = f32x4{0.f, 0.f, 0.f, 0.f};
  for (int ks = 0; ks < 8; ++ks) {
    const int k0 = ks * 32;
    int zbyte = ((rrow * 256 + k0 + kofs) * 2) ^ ((rrow & 7) << 4);
    bf16x8 a = *reinterpret_cast<const bf16x8*>((const char*)z_lds + zbyte);
#pragma unroll
    for (int nt = 0; nt < 4; ++nt) {
      int c = nt * 16 + l15;
      bf16x8 b = *reinterpret_cast<const bf16x8*>(Wt4 + (size_t)c * 256 + k0 + kofs);
      acc2[nt] = __builtin_amdgcn_mfma_f32_16x16x32_bf16(a, b, acc2[nt], 0, 0, 0);
    }
  }
#pragma unroll
  for (int nt = 0; nt < 4; ++nt) {
    float bv = b4[nt * 16 + l15];
#pragma unroll
    for (int r = 0; r < 4; ++r) acc2[nt][r] += bv;
  }

  float rinv[4];
#pragma unroll
  for (int r = 0; r < 4; ++r) {
    float ss = 0.0f;
#pragma unroll
    for (int nt = 0; nt < 4; ++nt) ss = fmaf(acc2[nt][r], acc2[nt][r], ss);
    ss += __shfl_xor(ss, 1);
    ss += __shfl_xor(ss, 2);
    ss += __shfl_xor(ss, 4);
    ss += __shfl_xor(ss, 8);
    rinv[r] = rsqrtf(ss);
  }
#pragma unroll
  for (int nt = 0; nt < 4; ++nt) {
    int c = nt * 16 + l15;
#pragma unroll
    for (int r = 0; r < 4; ++r) {
      int grow = row0 + wave * 16 + (lane >> 4) * 4 + r;
      if (grow < nrows)
        Out[(size_t)grow * 64 + c] = fmaxf(1e-6f, fabsf(acc2[nt][r]) * rinv[r]);
    }
  }
}

extern "C" void kernel_launch(void* const* d_in, const int* in_sizes, int n_in,
                              void* d_out, int out_size, void* d_ws, size_t ws_size,
                              hipStream_t stream) {
  const float* feat = (const float*)d_in[0];
  const int* src = (const int*)d_in[1];
  const int* dst = (const int*)d_in[2];
  const float* W1 = (const float*)d_in[3];
  const float* b1 = (const float*)d_in[4];
  const float* W2 = (const float*)d_in[5];
  const float* b2 = (const float*)d_in[6];
  const float* W3 = (const float*)d_in[7];
  const float* b3 = (const float*)d_in[8];
  const float* W4 = (const float*)d_in[9];
  const float* b4 = (const float*)d_in[10];
  float* out = (float*)d_out;

  char* ws = (char*)d_ws;
  size_t off = 0;
  auto alloc = [&](size_t bytes) {
    size_t p = off;
    off = (off + bytes + 255) & ~(size_t)255;
    return p;
  };
  float* ns = (float*)(ws + alloc((size_t)NN * 4));
  float* nd = (float*)(ws + alloc((size_t)NN * 4));
  int* row_off = (int*)(ws + alloc((size_t)(NN + 64) * 4));
  int* col = (int*)(ws + alloc((size_t)NE * 4));
  unsigned short* Wt1 = (unsigned short*)(ws + alloc((size_t)128 * 128 * 2));
  unsigned short* Wt2 = (unsigned short*)(ws + alloc((size_t)128 * 128 * 2));
  unsigned short* Wt3 = (unsigned short*)(ws + alloc((size_t)256 * 128 * 2));
  unsigned short* Wt4 = (unsigned short*)(ws + alloc((size_t)64 * 256 * 2));
  unsigned short* B0 = (unsigned short*)(ws + alloc((size_t)NN * 128 * 2));
  unsigned short* B1 = (unsigned short*)(ws + alloc((size_t)NN * 128 * 2));

  // CSR build temps live in B0 (prescale overwrites B0 only after scatter)
  int* degO = (int*)B0;
  int* degI = degO + NN;
  int* cursor = degI + NN;
  int* blk = cursor + NN;  // 128 ints

  hipMemsetAsync(degO, 0, 2 * (size_t)NN * 4, stream);

  // windowed degree count: 4 passes, counter windows (2 x 100KB) L2-resident
  constexpr int DWIN = 4;
  constexpr int DSZ = (NN + DWIN - 1) / DWIN;  // 25000
  for (int w = 0; w < DWIN; ++w) {
    degcnt_win_kernel<<<1024, 256, 0, stream>>>(src, dst, degO, degI, NE,
                                                w * DSZ, min(NN, (w + 1) * DSZ));
  }
  normi_kernel<<<(NN + 255) / 256, 256, 0, stream>>>(degO, degI, ns, nd, NN);
  const int nblk = (NN + 1023) / 1024;  // 98
  scan1_kernel<<<nblk, 1024, 0, stream>>>(degI, row_off, blk, NN);
  scan2_kernel<<<1, 128, 0, stream>>>(blk, nblk);
  scan3_kernel<<<nblk, 1024, 0, stream>>>(row_off, blk, cursor, NN, NE);

  // dst-windowed scatter: 4 passes (col window ~1.6MB + cursors L2-resident)
  constexpr int NWIN = 4;
  constexpr int WSZ = (NN + NWIN - 1) / NWIN;  // 25000
  for (int w = 0; w < NWIN; ++w) {
    scatter_win_kernel<<<1024, 256, 0, stream>>>(src, dst, cursor, col, NE,
                                                 w * WSZ, min(NN, (w + 1) * WSZ));
  }

  wconv_all_kernel<<<320, 256, 0, stream>>>(W1, Wt1, W2, Wt2, W3, Wt3, W4, Wt4);

  const int nGemmBlk = (NN + 63) / 64;
  const int aggBlocks = (NN * 64 + 255) / 256;

  prescale_kernel<<<(NN * 16 + 255) / 256, 256, 0, stream>>>(feat, ns, B0);
  agg_bf16_kernel<<<aggBlocks, 256, 0, stream>>>(B0, col, row_off, nd, B1, NN);
  gemm_mfma_kernel<128, 128><<<nGemmBlk, 256, 0, stream>>>(B1, Wt1, b1, ns, B0, NN);
  agg_bf16_kernel<<<aggBlocks, 256, 0, stream>>>(B0, col, row_off, nd, B1, NN);
  gemm_mfma_kernel<128, 128><<<nGemmBlk, 256, 0, stream>>>(B1, Wt2, b2, nullptr, B0, NN);
  mlp_mfma_kernel<<<nGemmBlk, 256, 0, stream>>>(B0, Wt3, b3, Wt4, b4, out, NN);
}

// Round 6
// 479.798 us; speedup vs baseline: 1.1618x; 1.1618x over previous
//
#include <hip/hip_runtime.h>

#define NN 100000
#define NE 1600000

typedef __bf16 bf16x8 __attribute__((ext_vector_type(8)));
typedef float f32x4 __attribute__((ext_vector_type(4)));

static __device__ __forceinline__ float bf2f_lo(unsigned int u) {
  return __uint_as_float(u << 16);
}
static __device__ __forceinline__ float bf2f_hi(unsigned int u) {
  return __uint_as_float(u & 0xffff0000u);
}
static __device__ __forceinline__ unsigned short f2bf(float f) {
  unsigned int u = __float_as_uint(f);
  unsigned int r = (u + 0x7fff + ((u >> 16) & 1)) >> 16;  // RNE
  return (unsigned short)r;
}

// ---------------- windowed degree accumulation ----------------
__global__ __launch_bounds__(256) void degcnt_win_kernel(
    const int* __restrict__ src, const int* __restrict__ dst,
    int* __restrict__ degO, int* __restrict__ degI, int nE, int w0, int w1) {
  int i = blockIdx.x * blockDim.x + threadIdx.x;
  int stride = gridDim.x * blockDim.x;
  for (int e = i; e < nE; e += stride) {
    int s = src[e];
    int d = dst[e];
    if (s >= w0 && s < w1) atomicAdd(&degO[s], 1);
    if (d >= w0 && d < w1) atomicAdd(&degI[d], 1);
  }
}

__global__ __launch_bounds__(256) void normi_kernel(
    const int* __restrict__ degO, const int* __restrict__ degI,
    float* __restrict__ ns, float* __restrict__ nd, int n) {
  int i = blockIdx.x * blockDim.x + threadIdx.x;
  if (i < n) {
    ns[i] = rsqrtf(fmaxf((float)degO[i], 1.0f));
    nd[i] = rsqrtf(fmaxf((float)degI[i], 1.0f));
  }
}

// ---------------- prefix scan ----------------
__global__ __launch_bounds__(1024) void scan1_kernel(
    const int* __restrict__ deg, int* __restrict__ excl,
    int* __restrict__ blk, int n) {
  __shared__ int lds[1024];
  const int tid = threadIdx.x;
  const int gid = blockIdx.x * 1024 + tid;
  int v = (gid < n) ? deg[gid] : 0;
  lds[tid] = v;
  __syncthreads();
  for (int off = 1; off < 1024; off <<= 1) {
    int t = (tid >= off) ? lds[tid - off] : 0;
    __syncthreads();
    lds[tid] += t;
    __syncthreads();
  }
  if (gid < n) excl[gid] = lds[tid] - v;
  if (tid == 1023) blk[blockIdx.x] = lds[1023];
}

__global__ __launch_bounds__(128) void scan2_kernel(int* __restrict__ blk, int nblk) {
  __shared__ int lds[128];
  const int tid = threadIdx.x;
  int v = (tid < nblk) ? blk[tid] : 0;
  lds[tid] = v;
  __syncthreads();
  for (int off = 1; off < 128; off <<= 1) {
    int t = (tid >= off) ? lds[tid - off] : 0;
    __syncthreads();
    lds[tid] += t;
    __syncthreads();
  }
  if (tid < nblk) blk[tid] = lds[tid] - v;
}

__global__ __launch_bounds__(1024) void scan3_kernel(
    int* __restrict__ row_off, const int* __restrict__ blk,
    int* __restrict__ cursor, int n, int nE) {
  int gid = blockIdx.x * 1024 + threadIdx.x;
  if (gid < n) {
    int v = row_off[gid] + blk[gid >> 10];
    row_off[gid] = v;
    cursor[gid] = v;
  }
  if (gid == 0) row_off[n] = nE;
}

// ---------------- dst-windowed CSR scatter ----------------
__global__ __launch_bounds__(256) void scatter_win_kernel(
    const int* __restrict__ src, const int* __restrict__ dst,
    int* __restrict__ cursor, int* __restrict__ col, int nE, int w0, int w1) {
  int i = blockIdx.x * blockDim.x + threadIdx.x;
  int stride = gridDim.x * blockDim.x;
  for (int e = i; e < nE; e += stride) {
    int d = dst[e];
    if (d >= w0 && d < w1) {
      int pos = atomicAdd(&cursor[d], 1);
      col[pos] = src[e];
    }
  }
}

// ---------------- all weights transpose+convert in one launch ----------------
__global__ __launch_bounds__(256) void wconv_all_kernel(
    const float* __restrict__ W1, unsigned short* __restrict__ Wt1,
    const float* __restrict__ W2, unsigned short* __restrict__ Wt2,
    const float* __restrict__ W3, unsigned short* __restrict__ Wt3,
    const float* __restrict__ W4, unsigned short* __restrict__ Wt4) {
  int gid = blockIdx.x * blockDim.x + threadIdx.x;
  const float* W;
  unsigned short* Wt;
  int K, C, i;
  if (gid < 16384) { W = W1; Wt = Wt1; K = 128; C = 128; i = gid; }
  else if (gid < 32768) { W = W2; Wt = Wt2; K = 128; C = 128; i = gid - 16384; }
  else if (gid < 65536) { W = W3; Wt = Wt3; K = 128; C = 256; i = gid - 32768; }
  else if (gid < 81920) { W = W4; Wt = Wt4; K = 256; C = 64; i = gid - 65536; }
  else return;
  int c = i % C, k = i / C;
  Wt[(size_t)c * K + k] = f2bf(W[i]);
}

// ---------------- prescale: out = bf16(feat * ns[row]) ----------------
__global__ __launch_bounds__(256) void prescale_kernel(
    const float* __restrict__ feat, const float* __restrict__ ns,
    unsigned short* __restrict__ out) {
  int idx = blockIdx.x * blockDim.x + threadIdx.x;
  if (idx >= NN * 16) return;
  int row = idx >> 4;
  int c8 = (idx & 15) * 8;
  float sc = ns[row];
  float4 v0 = *reinterpret_cast<const float4*>(feat + (size_t)row * 128 + c8);
  float4 v1 = *reinterpret_cast<const float4*>(feat + (size_t)row * 128 + c8 + 4);
  union { unsigned short u[8]; uint4 v; } p;
  p.u[0] = f2bf(v0.x * sc); p.u[1] = f2bf(v0.y * sc);
  p.u[2] = f2bf(v0.z * sc); p.u[3] = f2bf(v0.w * sc);
  p.u[4] = f2bf(v1.x * sc); p.u[5] = f2bf(v1.y * sc);
  p.u[6] = f2bf(v1.z * sc); p.u[7] = f2bf(v1.w * sc);
  *reinterpret_cast<uint4*>(out + (size_t)row * 128 + c8) = p.v;
}

// ---------------- CSR gather: out[d] = bf16(nd[d] * sum x[s]) ----------------
__global__ __launch_bounds__(256) void agg_bf16_kernel(
    const unsigned short* __restrict__ x, const int* __restrict__ col,
    const int* __restrict__ row_off, const float* __restrict__ nd,
    unsigned short* __restrict__ out, int nN) {
  const int wid = (blockIdx.x * blockDim.x + threadIdx.x) >> 6;
  const int lane = threadIdx.x & 63;
  if (wid >= nN) return;
  const int beg = row_off[wid];
  const int end = row_off[wid + 1];
  const int g = lane >> 3;
  const int lg = lane & 7;

  float acc[16] = {};
  for (int i0 = beg; i0 < end; i0 += 64) {
    const int cnt = min(64, end - i0);
    int myc = (lane < cnt) ? col[i0 + lane] : 0;
    for (int j = 0; j < cnt; j += 8) {
      int idx = j + g;
      int s = __shfl(myc, idx);
      float m = (idx < cnt) ? 1.0f : 0.0f;
      const uint4* p = reinterpret_cast<const uint4*>(x + (size_t)s * 128 + lg * 16);
      uint4 v0 = p[0];
      uint4 v1 = p[1];
      acc[0] = fmaf(m, bf2f_lo(v0.x), acc[0]);
      acc[1] = fmaf(m, bf2f_hi(v0.x), acc[1]);
      acc[2] = fmaf(m, bf2f_lo(v0.y), acc[2]);
      acc[3] = fmaf(m, bf2f_hi(v0.y), acc[3]);
      acc[4] = fmaf(m, bf2f_lo(v0.z), acc[4]);
      acc[5] = fmaf(m, bf2f_hi(v0.z), acc[5]);
      acc[6] = fmaf(m, bf2f_lo(v0.w), acc[6]);
      acc[7] = fmaf(m, bf2f_hi(v0.w), acc[7]);
      acc[8] = fmaf(m, bf2f_lo(v1.x), acc[8]);
      acc[9] = fmaf(m, bf2f_hi(v1.x), acc[9]);
      acc[10] = fmaf(m, bf2f_lo(v1.y), acc[10]);
      acc[11] = fmaf(m, bf2f_hi(v1.y), acc[11]);
      acc[12] = fmaf(m, bf2f_lo(v1.z), acc[12]);
      acc[13] = fmaf(m, bf2f_hi(v1.z), acc[13]);
      acc[14] = fmaf(m, bf2f_lo(v1.w), acc[14]);
      acc[15] = fmaf(m, bf2f_hi(v1.w), acc[15]);
    }
  }
#pragma unroll
  for (int k = 0; k < 16; ++k) {
    acc[k] += __shfl_xor(acc[k], 8);
    acc[k] += __shfl_xor(acc[k], 16);
    acc[k] += __shfl_xor(acc[k], 32);
  }
  if (g == 0) {
    float sc = nd[wid];
    union { unsigned short u[16]; uint4 v[2]; } p;
#pragma unroll
    for (int k = 0; k < 16; ++k) p.u[k] = f2bf(acc[k] * sc);
    uint4* o = reinterpret_cast<uint4*>(out + (size_t)wid * 128 + lg * 16);
    o[0] = p.v[0];
    o[1] = p.v[1];
  }
}

// ---------------- MFMA GEMM with LDS-staged B ----------------
// A:[nrows,128] bf16, Wt:[128,128] bf16 (transposed, linear-stageable)
__global__ __launch_bounds__(256) void gemm_mfma_kernel(
    const unsigned short* __restrict__ A, const unsigned short* __restrict__ Wt,
    const float* __restrict__ bias, const float* __restrict__ postscale,
    unsigned short* __restrict__ C, int nrows) {
  constexpr int K = 128, COLS = 128, TM = 64;
  constexpr int NT = COLS / 16;  // 8
  __shared__ unsigned short a_lds[TM * K];    // 16KB, 256B rows
  __shared__ unsigned short b_lds[COLS * K];  // 32KB, 256B rows
  const int row0 = blockIdx.x * TM;
  const int tid = threadIdx.x;
  const int wave = tid >> 6, lane = tid & 63;

  // stage A (swizzled)
  for (int i = tid; i < TM * K * 2 / 16; i += 256) {
    int byte_lin = i * 16;
    int r = byte_lin >> 8;
    int swz = byte_lin ^ ((r & 7) << 4);
    uint4 v = {0u, 0u, 0u, 0u};
    int gr = row0 + r;
    if (gr < nrows)
      v = *reinterpret_cast<const uint4*>(A + (size_t)gr * K + (byte_lin & 255) / 2);
    *reinterpret_cast<uint4*>((char*)a_lds + swz) = v;
  }
  // stage B: Wt layout [c][k] is linear in byte_lin (256B rows); coalesced
  for (int i = tid; i < COLS * K * 2 / 16; i += 256) {
    int byte_lin = i * 16;
    int r = byte_lin >> 8;
    int swz = byte_lin ^ ((r & 7) << 4);
    *reinterpret_cast<uint4*>((char*)b_lds + swz) =
        *reinterpret_cast<const uint4*>((const char*)Wt + byte_lin);
  }
  __syncthreads();

  const int rrow = wave * 16 + (lane & 15);
  const int kofs = (lane >> 4) * 8;
  f32x4 acc[NT];
#pragma unroll
  for (int nt = 0; nt < NT; ++nt) acc[nt] = f32x4{0.f, 0.f, 0.f, 0.f};

  for (int ks = 0; ks < 4; ++ks) {
    const int k0 = ks * 32;
    int abyte = ((rrow * K + k0 + kofs) * 2) ^ ((rrow & 7) << 4);
    bf16x8 a = *reinterpret_cast<const bf16x8*>((const char*)a_lds + abyte);
#pragma unroll
    for (int nt = 0; nt < NT; ++nt) {
      int c = nt * 16 + (lane & 15);
      int bbyte = ((c * K + k0 + kofs) * 2) ^ ((c & 7) << 4);
      bf16x8 b = *reinterpret_cast<const bf16x8*>((const char*)b_lds + bbyte);
      acc[nt] = __builtin_amdgcn_mfma_f32_16x16x32_bf16(a, b, acc[nt], 0, 0, 0);
    }
  }

  __syncthreads();
#pragma unroll
  for (int nt = 0; nt < NT; ++nt) {
    int c = nt * 16 + (lane & 15);
    float bv = bias[c];
#pragma unroll
    for (int r = 0; r < 4; ++r) {
      int lrow = wave * 16 + (lane >> 4) * 4 + r;
      int grow = row0 + lrow;
      float ps = (postscale != nullptr && grow < nrows) ? postscale[grow] : 1.0f;
      float v = (acc[nt][r] + bv) * ps;
      a_lds[lrow * COLS + c] = f2bf(v);
    }
  }
  __syncthreads();
  for (int i = tid; i < TM * COLS * 2 / 16; i += 256) {
    int byte_lin = i * 16;
    int r = byte_lin / (COLS * 2);
    int gr = row0 + r;
    if (gr < nrows)
      *reinterpret_cast<uint4*>(C + (size_t)gr * COLS + (byte_lin % (COLS * 2)) / 2) =
          *reinterpret_cast<const uint4*>((const char*)a_lds + byte_lin);
  }
}

// ---------------- fused MLP + proj, LDS-staged B (80KB plan) ----------------
// smem: h[0:16K) | b0[16K:32K) | b1[32K:48K) | z[48K:80K); w4 overlays [0:32K)
__global__ __launch_bounds__(256) void mlp_mfma_kernel(
    const unsigned short* __restrict__ H, const unsigned short* __restrict__ Wt3,
    const float* __restrict__ b3, const unsigned short* __restrict__ Wt4,
    const float* __restrict__ b4, float* __restrict__ Out, int nrows) {
  constexpr int TM = 64;
  __shared__ char smem[81920];
  unsigned short* h_lds = (unsigned short*)smem;
  char* bbuf[2] = {smem + 16384, smem + 32768};
  char* z_base = smem + 49152;
  const int row0 = blockIdx.x * TM;
  const int tid = threadIdx.x;
  const int wave = tid >> 6, lane = tid & 63;
  const int l15 = lane & 15;
  const int kofs = (lane >> 4) * 8;

  // stage H (256B rows, swizzled)
  for (int i = tid; i < TM * 128 * 2 / 16; i += 256) {
    int byte_lin = i * 16;
    int r = byte_lin >> 8;
    int swz = byte_lin ^ ((r & 7) << 4);
    uint4 v = {0u, 0u, 0u, 0u};
    int gr = row0 + r;
    if (gr < nrows)
      v = *reinterpret_cast<const uint4*>(H + (size_t)gr * 128 + (byte_lin & 255) / 2);
    *reinterpret_cast<uint4*>((char*)h_lds + swz) = v;
  }

  // stage Wt3 ks-chunk: [256 c-rows][64B], swizzle ^(((r>>1)&3)<<4)
  auto stage_b3 = [&](int ks, char* dstb) {
#pragma unroll
    for (int it = 0; it < 4; ++it) {
      int byte_lin = (tid + it * 256) * 16;
      int r = byte_lin >> 6;
      int kb = byte_lin & 63;
      int swz = byte_lin ^ (((r >> 1) & 3) << 4);
      *reinterpret_cast<uint4*>(dstb + swz) =
          *reinterpret_cast<const uint4*>((const char*)Wt3 + r * 256 + ks * 64 + kb);
    }
  };
  stage_b3(0, bbuf[0]);
  __syncthreads();

  const int rrow = wave * 16 + l15;
  // phase 1: z = relu(H @ W3 + b3)
  {
    f32x4 acc[16];
#pragma unroll
    for (int nt = 0; nt < 16; ++nt) acc[nt] = f32x4{0.f, 0.f, 0.f, 0.f};
    for (int ks = 0; ks < 4; ++ks) {
      if (ks < 3) stage_b3(ks + 1, bbuf[(ks + 1) & 1]);
      const char* bl = bbuf[ks & 1];
      int abyte = ((rrow * 128 + ks * 32 + kofs) * 2) ^ ((rrow & 7) << 4);
      bf16x8 a = *reinterpret_cast<const bf16x8*>((const char*)h_lds + abyte);
#pragma unroll
      for (int nt = 0; nt < 16; ++nt) {
        int c = nt * 16 + l15;
        int bbyte = (c * 64 + (kofs / 8) * 16) ^ (((c >> 1) & 3) << 4);
        bf16x8 b = *reinterpret_cast<const bf16x8*>(bl + bbyte);
        acc[nt] = __builtin_amdgcn_mfma_f32_16x16x32_bf16(a, b, acc[nt], 0, 0, 0);
      }
      __syncthreads();
    }
    // write z (512B rows, swizzled)
#pragma unroll
    for (int nt = 0; nt < 16; ++nt) {
      int c = nt * 16 + l15;
      float bv = b3[c];
#pragma unroll
      for (int r = 0; r < 4; ++r) {
        int lrow = wave * 16 + (lane >> 4) * 4 + r;
        float v = fmaxf(acc[nt][r] + bv, 0.0f);
        int zb = (lrow * 512 + c * 2) ^ ((lrow & 7) << 4);
        *reinterpret_cast<unsigned short*>(z_base + zb) = f2bf(v);
      }
    }
  }
  __syncthreads();

  // stage Wt4 [64 c2-rows][512B] into smem[0:32K) — global layout linear
  char* w4 = smem;
  for (int it = 0; it < 8; ++it) {
    int byte_lin = (tid + it * 256) * 16;
    int r = byte_lin >> 9;
    int swz = byte_lin ^ ((r & 7) << 4);
    *reinterpret_cast<uint4*>(w4 + swz) =
        *reinterpret_cast<const uint4*>((const char*)Wt4 + byte_lin);
  }
  __syncthreads();

  // phase 2: y = z @ W4 + b4, then proj
  f32x4 acc2[4];
#pragma unroll
  for (int nt = 0; nt < 4; ++nt) acc2[nt] = f32x4{0.f, 0.f, 0.f, 0.f};
  for (int ks = 0; ks < 8; ++ks) {
    const int k0 = ks * 32;
    int zbyte = ((rrow * 256 + k0 + kofs) * 2) ^ ((rrow & 7) << 4);
    bf16x8 a = *reinterpret_cast<const bf16x8*>(z_base + zbyte);
#pragma unroll
    for (int nt = 0; nt < 4; ++nt) {
      int c = nt * 16 + l15;
      int wbyte = (c * 512 + (k0 + kofs) * 2) ^ ((c & 7) << 4);
      bf16x8 b = *reinterpret_cast<const bf16x8*>(w4 + wbyte);
      acc2[nt] = __builtin_amdgcn_mfma_f32_16x16x32_bf16(a, b, acc2[nt], 0, 0, 0);
    }
  }
#pragma unroll
  for (int nt = 0; nt < 4; ++nt) {
    float bv = b4[nt * 16 + l15];
#pragma unroll
    for (int r = 0; r < 4; ++r) acc2[nt][r] += bv;
  }

  float rinv[4];
#pragma unroll
  for (int r = 0; r < 4; ++r) {
    float ss = 0.0f;
#pragma unroll
    for (int nt = 0; nt < 4; ++nt) ss = fmaf(acc2[nt][r], acc2[nt][r], ss);
    ss += __shfl_xor(ss, 1);
    ss += __shfl_xor(ss, 2);
    ss += __shfl_xor(ss, 4);
    ss += __shfl_xor(ss, 8);
    rinv[r] = rsqrtf(ss);
  }
#pragma unroll
  for (int nt = 0; nt < 4; ++nt) {
    int c = nt * 16 + l15;
#pragma unroll
    for (int r = 0; r < 4; ++r) {
      int grow = row0 + wave * 16 + (lane >> 4) * 4 + r;
      if (grow < nrows)
        Out[(size_t)grow * 64 + c] = fmaxf(1e-6f, fabsf(acc2[nt][r]) * rinv[r]);
    }
  }
}

extern "C" void kernel_launch(void* const* d_in, const int* in_sizes, int n_in,
                              void* d_out, int out_size, void* d_ws, size_t ws_size,
                              hipStream_t stream) {
  const float* feat = (const float*)d_in[0];
  const int* src = (const int*)d_in[1];
  const int* dst = (const int*)d_in[2];
  const float* W1 = (const float*)d_in[3];
  const float* b1 = (const float*)d_in[4];
  const float* W2 = (const float*)d_in[5];
  const float* b2 = (const float*)d_in[6];
  const float* W3 = (const float*)d_in[7];
  const float* b3 = (const float*)d_in[8];
  const float* W4 = (const float*)d_in[9];
  const float* b4 = (const float*)d_in[10];
  float* out = (float*)d_out;

  char* ws = (char*)d_ws;
  size_t off = 0;
  auto alloc = [&](size_t bytes) {
    size_t p = off;
    off = (off + bytes + 255) & ~(size_t)255;
    return p;
  };
  float* ns = (float*)(ws + alloc((size_t)NN * 4));
  float* nd = (float*)(ws + alloc((size_t)NN * 4));
  int* row_off = (int*)(ws + alloc((size_t)(NN + 64) * 4));
  int* col = (int*)(ws + alloc((size_t)NE * 4));
  unsigned short* Wt1 = (unsigned short*)(ws + alloc((size_t)128 * 128 * 2));
  unsigned short* Wt2 = (unsigned short*)(ws + alloc((size_t)128 * 128 * 2));
  unsigned short* Wt3 = (unsigned short*)(ws + alloc((size_t)256 * 128 * 2));
  unsigned short* Wt4 = (unsigned short*)(ws + alloc((size_t)64 * 256 * 2));
  unsigned short* B0 = (unsigned short*)(ws + alloc((size_t)NN * 128 * 2));
  unsigned short* B1 = (unsigned short*)(ws + alloc((size_t)NN * 128 * 2));

  int* degO = (int*)B0;
  int* degI = degO + NN;
  int* cursor = degI + NN;
  int* blk = cursor + NN;

  hipMemsetAsync(degO, 0, 2 * (size_t)NN * 4, stream);

  constexpr int DWIN = 4;
  constexpr int DSZ = (NN + DWIN - 1) / DWIN;
  for (int w = 0; w < DWIN; ++w) {
    degcnt_win_kernel<<<1024, 256, 0, stream>>>(src, dst, degO, degI, NE,
                                                w * DSZ, min(NN, (w + 1) * DSZ));
  }
  normi_kernel<<<(NN + 255) / 256, 256, 0, stream>>>(degO, degI, ns, nd, NN);
  const int nblk = (NN + 1023) / 1024;
  scan1_kernel<<<nblk, 1024, 0, stream>>>(degI, row_off, blk, NN);
  scan2_kernel<<<1, 128, 0, stream>>>(blk, nblk);
  scan3_kernel<<<nblk, 1024, 0, stream>>>(row_off, blk, cursor, NN, NE);

  constexpr int NWIN = 4;
  constexpr int WSZ = (NN + NWIN - 1) / NWIN;
  for (int w = 0; w < NWIN; ++w) {
    scatter_win_kernel<<<1024, 256, 0, stream>>>(src, dst, cursor, col, NE,
                                                 w * WSZ, min(NN, (w + 1) * WSZ));
  }

  wconv_all_kernel<<<320, 256, 0, stream>>>(W1, Wt1, W2, Wt2, W3, Wt3, W4, Wt4);

  const int nGemmBlk = (NN + 63) / 64;
  const int aggBlocks = (NN * 64 + 255) / 256;

  prescale_kernel<<<(NN * 16 + 255) / 256, 256, 0, stream>>>(feat, ns, B0);
  agg_bf16_kernel<<<aggBlocks, 256, 0, stream>>>(B0, col, row_off, nd, B1, NN);
  gemm_mfma_kernel<<<nGemmBlk, 256, 0, stream>>>(B1, Wt1, b1, ns, B0, NN);
  agg_bf16_kernel<<<aggBlocks, 256, 0, stream>>>(B0, col, row_off, nd, B1, NN);
  gemm_mfma_kernel<<<nGemmBlk, 256, 0, stream>>>(B1, Wt2, b2, nullptr, B0, NN);
  mlp_mfma_kernel<<<nGemmBlk, 256, 0, stream>>>(B0, Wt3, b3, Wt4, b4, out, NN);
}

// Round 7
// 436.217 us; speedup vs baseline: 1.2779x; 1.0999x over previous
//
#include <hip/hip_runtime.h>

#define NN 100000
#define NE 1600000

typedef __bf16 bf16x8 __attribute__((ext_vector_type(8)));
typedef float f32x4 __attribute__((ext_vector_type(4)));

static __device__ __forceinline__ float bf2f_lo(unsigned int u) {
  return __uint_as_float(u << 16);
}
static __device__ __forceinline__ float bf2f_hi(unsigned int u) {
  return __uint_as_float(u & 0xffff0000u);
}
static __device__ __forceinline__ unsigned short f2bf(float f) {
  unsigned int u = __float_as_uint(f);
  unsigned int r = (u + 0x7fff + ((u >> 16) & 1)) >> 16;  // RNE
  return (unsigned short)r;
}

// ---------------- XCD-pinned degree accumulation (single launch) ----------------
// blockIdx&7 selects a node window; with the %8 block->XCD round-robin, all
// atomics to a window issue from one XCD -> counter lines stay in that L2.
__global__ __launch_bounds__(256) void degcnt_xcd_kernel(
    const int* __restrict__ src, const int* __restrict__ dst,
    int* __restrict__ degO, int* __restrict__ degI, int nE) {
  const int w0 = (blockIdx.x & 7) * (NN / 8);
  const int w1 = w0 + (NN / 8);
  int i = (blockIdx.x >> 3) * blockDim.x + threadIdx.x;
  int stride = (gridDim.x >> 3) * blockDim.x;
  for (int e = i; e < nE; e += stride) {
    int s = src[e];
    int d = dst[e];
    if (s >= w0 && s < w1) atomicAdd(&degO[s], 1);
    if (d >= w0 && d < w1) atomicAdd(&degI[d], 1);
  }
}

__global__ __launch_bounds__(256) void normi_kernel(
    const int* __restrict__ degO, const int* __restrict__ degI,
    float* __restrict__ ns, float* __restrict__ nd, int n) {
  int i = blockIdx.x * blockDim.x + threadIdx.x;
  if (i < n) {
    ns[i] = rsqrtf(fmaxf((float)degO[i], 1.0f));
    nd[i] = rsqrtf(fmaxf((float)degI[i], 1.0f));
  }
}

// ---------------- prefix scan ----------------
__global__ __launch_bounds__(1024) void scan1_kernel(
    const int* __restrict__ deg, int* __restrict__ excl,
    int* __restrict__ blk, int n) {
  __shared__ int lds[1024];
  const int tid = threadIdx.x;
  const int gid = blockIdx.x * 1024 + tid;
  int v = (gid < n) ? deg[gid] : 0;
  lds[tid] = v;
  __syncthreads();
  for (int off = 1; off < 1024; off <<= 1) {
    int t = (tid >= off) ? lds[tid - off] : 0;
    __syncthreads();
    lds[tid] += t;
    __syncthreads();
  }
  if (gid < n) excl[gid] = lds[tid] - v;
  if (tid == 1023) blk[blockIdx.x] = lds[1023];
}

__global__ __launch_bounds__(128) void scan2_kernel(int* __restrict__ blk, int nblk) {
  __shared__ int lds[128];
  const int tid = threadIdx.x;
  int v = (tid < nblk) ? blk[tid] : 0;
  lds[tid] = v;
  __syncthreads();
  for (int off = 1; off < 128; off <<= 1) {
    int t = (tid >= off) ? lds[tid - off] : 0;
    __syncthreads();
    lds[tid] += t;
    __syncthreads();
  }
  if (tid < nblk) blk[tid] = lds[tid] - v;
}

__global__ __launch_bounds__(1024) void scan3_kernel(
    int* __restrict__ row_off, const int* __restrict__ blk,
    int* __restrict__ cursor, int n, int nE) {
  int gid = blockIdx.x * 1024 + threadIdx.x;
  if (gid < n) {
    int v = row_off[gid] + blk[gid >> 10];
    row_off[gid] = v;
    cursor[gid] = v;
  }
  if (gid == 0) row_off[n] = nE;
}

// ---------------- XCD-pinned CSR scatter (single launch) ----------------
__global__ __launch_bounds__(256) void scatter_xcd_kernel(
    const int* __restrict__ src, const int* __restrict__ dst,
    int* __restrict__ cursor, int* __restrict__ col, int nE) {
  const int w0 = (blockIdx.x & 7) * (NN / 8);
  const int w1 = w0 + (NN / 8);
  int i = (blockIdx.x >> 3) * blockDim.x + threadIdx.x;
  int stride = (gridDim.x >> 3) * blockDim.x;
  for (int e = i; e < nE; e += stride) {
    int d = dst[e];
    if (d >= w0 && d < w1) {
      int pos = atomicAdd(&cursor[d], 1);
      col[pos] = src[e];
    }
  }
}

// ---------------- all weights transpose+convert in one launch ----------------
__global__ __launch_bounds__(256) void wconv_all_kernel(
    const float* __restrict__ W1, unsigned short* __restrict__ Wt1,
    const float* __restrict__ W2, unsigned short* __restrict__ Wt2,
    const float* __restrict__ W3, unsigned short* __restrict__ Wt3,
    const float* __restrict__ W4, unsigned short* __restrict__ Wt4) {
  int gid = blockIdx.x * blockDim.x + threadIdx.x;
  const float* W;
  unsigned short* Wt;
  int K, C, i;
  if (gid < 16384) { W = W1; Wt = Wt1; K = 128; C = 128; i = gid; }
  else if (gid < 32768) { W = W2; Wt = Wt2; K = 128; C = 128; i = gid - 16384; }
  else if (gid < 65536) { W = W3; Wt = Wt3; K = 128; C = 256; i = gid - 32768; }
  else if (gid < 81920) { W = W4; Wt = Wt4; K = 256; C = 64; i = gid - 65536; }
  else return;
  int c = i % C, k = i / C;
  Wt[(size_t)c * K + k] = f2bf(W[i]);
}

// ---------------- prescale: out = bf16(feat * ns[row]) ----------------
__global__ __launch_bounds__(256) void prescale_kernel(
    const float* __restrict__ feat, const float* __restrict__ ns,
    unsigned short* __restrict__ out) {
  int idx = blockIdx.x * blockDim.x + threadIdx.x;
  if (idx >= NN * 16) return;
  int row = idx >> 4;
  int c8 = (idx & 15) * 8;
  float sc = ns[row];
  float4 v0 = *reinterpret_cast<const float4*>(feat + (size_t)row * 128 + c8);
  float4 v1 = *reinterpret_cast<const float4*>(feat + (size_t)row * 128 + c8 + 4);
  union { unsigned short u[8]; uint4 v; } p;
  p.u[0] = f2bf(v0.x * sc); p.u[1] = f2bf(v0.y * sc);
  p.u[2] = f2bf(v0.z * sc); p.u[3] = f2bf(v0.w * sc);
  p.u[4] = f2bf(v1.x * sc); p.u[5] = f2bf(v1.y * sc);
  p.u[6] = f2bf(v1.z * sc); p.u[7] = f2bf(v1.w * sc);
  *reinterpret_cast<uint4*>(out + (size_t)row * 128 + c8) = p.v;
}

// ---------------- CSR gather: out[d] = bf16(nd[d] * sum x[s]) ----------------
__global__ __launch_bounds__(256) void agg_bf16_kernel(
    const unsigned short* __restrict__ x, const int* __restrict__ col,
    const int* __restrict__ row_off, const float* __restrict__ nd,
    unsigned short* __restrict__ out, int nN) {
  const int wid = (blockIdx.x * blockDim.x + threadIdx.x) >> 6;
  const int lane = threadIdx.x & 63;
  if (wid >= nN) return;
  const int beg = row_off[wid];
  const int end = row_off[wid + 1];
  const int g = lane >> 3;
  const int lg = lane & 7;

  float acc[16] = {};
  for (int i0 = beg; i0 < end; i0 += 64) {
    const int cnt = min(64, end - i0);
    int myc = (lane < cnt) ? col[i0 + lane] : 0;
    for (int j = 0; j < cnt; j += 8) {
      int idx = j + g;
      int s = __shfl(myc, idx);
      float m = (idx < cnt) ? 1.0f : 0.0f;
      const uint4* p = reinterpret_cast<const uint4*>(x + (size_t)s * 128 + lg * 16);
      uint4 v0 = p[0];
      uint4 v1 = p[1];
      acc[0] = fmaf(m, bf2f_lo(v0.x), acc[0]);
      acc[1] = fmaf(m, bf2f_hi(v0.x), acc[1]);
      acc[2] = fmaf(m, bf2f_lo(v0.y), acc[2]);
      acc[3] = fmaf(m, bf2f_hi(v0.y), acc[3]);
      acc[4] = fmaf(m, bf2f_lo(v0.z), acc[4]);
      acc[5] = fmaf(m, bf2f_hi(v0.z), acc[5]);
      acc[6] = fmaf(m, bf2f_lo(v0.w), acc[6]);
      acc[7] = fmaf(m, bf2f_hi(v0.w), acc[7]);
      acc[8] = fmaf(m, bf2f_lo(v1.x), acc[8]);
      acc[9] = fmaf(m, bf2f_hi(v1.x), acc[9]);
      acc[10] = fmaf(m, bf2f_lo(v1.y), acc[10]);
      acc[11] = fmaf(m, bf2f_hi(v1.y), acc[11]);
      acc[12] = fmaf(m, bf2f_lo(v1.z), acc[12]);
      acc[13] = fmaf(m, bf2f_hi(v1.z), acc[13]);
      acc[14] = fmaf(m, bf2f_lo(v1.w), acc[14]);
      acc[15] = fmaf(m, bf2f_hi(v1.w), acc[15]);
    }
  }
#pragma unroll
  for (int k = 0; k < 16; ++k) {
    acc[k] += __shfl_xor(acc[k], 8);
    acc[k] += __shfl_xor(acc[k], 16);
    acc[k] += __shfl_xor(acc[k], 32);
  }
  if (g == 0) {
    float sc = nd[wid];
    union { unsigned short u[16]; uint4 v[2]; } p;
#pragma unroll
    for (int k = 0; k < 16; ++k) p.u[k] = f2bf(acc[k] * sc);
    uint4* o = reinterpret_cast<uint4*>(out + (size_t)wid * 128 + lg * 16);
    o[0] = p.v[0];
    o[1] = p.v[1];
  }
}

// ---------------- MFMA GEMM with LDS-staged B ----------------
__global__ __launch_bounds__(256) void gemm_mfma_kernel(
    const unsigned short* __restrict__ A, const unsigned short* __restrict__ Wt,
    const float* __restrict__ bias, const float* __restrict__ postscale,
    unsigned short* __restrict__ C, int nrows) {
  constexpr int K = 128, COLS = 128, TM = 64;
  constexpr int NT = COLS / 16;  // 8
  __shared__ unsigned short a_lds[TM * K];
  __shared__ unsigned short b_lds[COLS * K];
  const int row0 = blockIdx.x * TM;
  const int tid = threadIdx.x;
  const int wave = tid >> 6, lane = tid & 63;

  for (int i = tid; i < TM * K * 2 / 16; i += 256) {
    int byte_lin = i * 16;
    int r = byte_lin >> 8;
    int swz = byte_lin ^ ((r & 7) << 4);
    uint4 v = {0u, 0u, 0u, 0u};
    int gr = row0 + r;
    if (gr < nrows)
      v = *reinterpret_cast<const uint4*>(A + (size_t)gr * K + (byte_lin & 255) / 2);
    *reinterpret_cast<uint4*>((char*)a_lds + swz) = v;
  }
  for (int i = tid; i < COLS * K * 2 / 16; i += 256) {
    int byte_lin = i * 16;
    int r = byte_lin >> 8;
    int swz = byte_lin ^ ((r & 7) << 4);
    *reinterpret_cast<uint4*>((char*)b_lds + swz) =
        *reinterpret_cast<const uint4*>((const char*)Wt + byte_lin);
  }
  __syncthreads();

  const int rrow = wave * 16 + (lane & 15);
  const int kofs = (lane >> 4) * 8;
  f32x4 acc[NT];
#pragma unroll
  for (int nt = 0; nt < NT; ++nt) acc[nt] = f32x4{0.f, 0.f, 0.f, 0.f};

  for (int ks = 0; ks < 4; ++ks) {
    const int k0 = ks * 32;
    int abyte = ((rrow * K + k0 + kofs) * 2) ^ ((rrow & 7) << 4);
    bf16x8 a = *reinterpret_cast<const bf16x8*>((const char*)a_lds + abyte);
#pragma unroll
    for (int nt = 0; nt < NT; ++nt) {
      int c = nt * 16 + (lane & 15);
      int bbyte = ((c * K + k0 + kofs) * 2) ^ ((c & 7) << 4);
      bf16x8 b = *reinterpret_cast<const bf16x8*>((const char*)b_lds + bbyte);
      acc[nt] = __builtin_amdgcn_mfma_f32_16x16x32_bf16(a, b, acc[nt], 0, 0, 0);
    }
  }

  __syncthreads();
#pragma unroll
  for (int nt = 0; nt < NT; ++nt) {
    int c = nt * 16 + (lane & 15);
    float bv = bias[c];
#pragma unroll
    for (int r = 0; r < 4; ++r) {
      int lrow = wave * 16 + (lane >> 4) * 4 + r;
      int grow = row0 + lrow;
      float ps = (postscale != nullptr && grow < nrows) ? postscale[grow] : 1.0f;
      float v = (acc[nt][r] + bv) * ps;
      a_lds[lrow * COLS + c] = f2bf(v);
    }
  }
  __syncthreads();
  for (int i = tid; i < TM * COLS * 2 / 16; i += 256) {
    int byte_lin = i * 16;
    int r = byte_lin / (COLS * 2);
    int gr = row0 + r;
    if (gr < nrows)
      *reinterpret_cast<uint4*>(C + (size_t)gr * COLS + (byte_lin % (COLS * 2)) / 2) =
          *reinterpret_cast<const uint4*>((const char*)a_lds + byte_lin);
  }
}

// ---------------- fused MLP + proj, LDS-staged B (80KB plan) ----------------
__global__ __launch_bounds__(256) void mlp_mfma_kernel(
    const unsigned short* __restrict__ H, const unsigned short* __restrict__ Wt3,
    const float* __restrict__ b3, const unsigned short* __restrict__ Wt4,
    const float* __restrict__ b4, float* __restrict__ Out, int nrows) {
  constexpr int TM = 64;
  __shared__ char smem[81920];
  unsigned short* h_lds = (unsigned short*)smem;
  char* bbuf[2] = {smem + 16384, smem + 32768};
  char* z_base = smem + 49152;
  const int row0 = blockIdx.x * TM;
  const int tid = threadIdx.x;
  const int wave = tid >> 6, lane = tid & 63;
  const int l15 = lane & 15;
  const int kofs = (lane >> 4) * 8;

  for (int i = tid; i < TM * 128 * 2 / 16; i += 256) {
    int byte_lin = i * 16;
    int r = byte_lin >> 8;
    int swz = byte_lin ^ ((r & 7) << 4);
    uint4 v = {0u, 0u, 0u, 0u};
    int gr = row0 + r;
    if (gr < nrows)
      v = *reinterpret_cast<const uint4*>(H + (size_t)gr * 128 + (byte_lin & 255) / 2);
    *reinterpret_cast<uint4*>((char*)h_lds + swz) = v;
  }

  auto stage_b3 = [&](int ks, char* dstb) {
#pragma unroll
    for (int it = 0; it < 4; ++it) {
      int byte_lin = (tid + it * 256) * 16;
      int r = byte_lin >> 6;
      int kb = byte_lin & 63;
      int swz = byte_lin ^ (((r >> 1) & 3) << 4);
      *reinterpret_cast<uint4*>(dstb + swz) =
          *reinterpret_cast<const uint4*>((const char*)Wt3 + r * 256 + ks * 64 + kb);
    }
  };
  stage_b3(0, bbuf[0]);
  __syncthreads();

  const int rrow = wave * 16 + l15;
  {
    f32x4 acc[16];
#pragma unroll
    for (int nt = 0; nt < 16; ++nt) acc[nt] = f32x4{0.f, 0.f, 0.f, 0.f};
    for (int ks = 0; ks < 4; ++ks) {
      if (ks < 3) stage_b3(ks + 1, bbuf[(ks + 1) & 1]);
      const char* bl = bbuf[ks & 1];
      int abyte = ((rrow * 128 + ks * 32 + kofs) * 2) ^ ((rrow & 7) << 4);
      bf16x8 a = *reinterpret_cast<const bf16x8*>((const char*)h_lds + abyte);
#pragma unroll
      for (int nt = 0; nt < 16; ++nt) {
        int c = nt * 16 + l15;
        int bbyte = (c * 64 + (kofs / 8) * 16) ^ (((c >> 1) & 3) << 4);
        bf16x8 b = *reinterpret_cast<const bf16x8*>(bl + bbyte);
        acc[nt] = __builtin_amdgcn_mfma_f32_16x16x32_bf16(a, b, acc[nt], 0, 0, 0);
      }
      __syncthreads();
    }
#pragma unroll
    for (int nt = 0; nt < 16; ++nt) {
      int c = nt * 16 + l15;
      float bv = b3[c];
#pragma unroll
      for (int r = 0; r < 4; ++r) {
        int lrow = wave * 16 + (lane >> 4) * 4 + r;
        float v = fmaxf(acc[nt][r] + bv, 0.0f);
        int zb = (lrow * 512 + c * 2) ^ ((lrow & 7) << 4);
        *reinterpret_cast<unsigned short*>(z_base + zb) = f2bf(v);
      }
    }
  }
  __syncthreads();

  char* w4 = smem;
  for (int it = 0; it < 8; ++it) {
    int byte_lin = (tid + it * 256) * 16;
    int r = byte_lin >> 9;
    int swz = byte_lin ^ ((r & 7) << 4);
    *reinterpret_cast<uint4*>(w4 + swz) =
        *reinterpret_cast<const uint4*>((const char*)Wt4 + byte_lin);
  }
  __syncthreads();

  f32x4 acc2[4];
#pragma unroll
  for (int nt = 0; nt < 4; ++nt) acc2[nt] = f32x4{0.f, 0.f, 0.f, 0.f};
  for (int ks = 0; ks < 8; ++ks) {
    const int k0 = ks * 32;
    int zbyte = ((rrow * 256 + k0 + kofs) * 2) ^ ((rrow & 7) << 4);
    bf16x8 a = *reinterpret_cast<const bf16x8*>(z_base + zbyte);
#pragma unroll
    for (int nt = 0; nt < 4; ++nt) {
      int c = nt * 16 + l15;
      int wbyte = (c * 512 + (k0 + kofs) * 2) ^ ((c & 7) << 4);
      bf16x8 b = *reinterpret_cast<const bf16x8*>(w4 + wbyte);
      acc2[nt] = __builtin_amdgcn_mfma_f32_16x16x32_bf16(a, b, acc2[nt], 0, 0, 0);
    }
  }
#pragma unroll
  for (int nt = 0; nt < 4; ++nt) {
    float bv = b4[nt * 16 + l15];
#pragma unroll
    for (int r = 0; r < 4; ++r) acc2[nt][r] += bv;
  }

  float rinv[4];
#pragma unroll
  for (int r = 0; r < 4; ++r) {
    float ss = 0.0f;
#pragma unroll
    for (int nt = 0; nt < 4; ++nt) ss = fmaf(acc2[nt][r], acc2[nt][r], ss);
    ss += __shfl_xor(ss, 1);
    ss += __shfl_xor(ss, 2);
    ss += __shfl_xor(ss, 4);
    ss += __shfl_xor(ss, 8);
    rinv[r] = rsqrtf(ss);
  }
#pragma unroll
  for (int nt = 0; nt < 4; ++nt) {
    int c = nt * 16 + l15;
#pragma unroll
    for (int r = 0; r < 4; ++r) {
      int grow = row0 + wave * 16 + (lane >> 4) * 4 + r;
      if (grow < nrows)
        Out[(size_t)grow * 64 + c] = fmaxf(1e-6f, fabsf(acc2[nt][r]) * rinv[r]);
    }
  }
}

extern "C" void kernel_launch(void* const* d_in, const int* in_sizes, int n_in,
                              void* d_out, int out_size, void* d_ws, size_t ws_size,
                              hipStream_t stream) {
  const float* feat = (const float*)d_in[0];
  const int* src = (const int*)d_in[1];
  const int* dst = (const int*)d_in[2];
  const float* W1 = (const float*)d_in[3];
  const float* b1 = (const float*)d_in[4];
  const float* W2 = (const float*)d_in[5];
  const float* b2 = (const float*)d_in[6];
  const float* W3 = (const float*)d_in[7];
  const float* b3 = (const float*)d_in[8];
  const float* W4 = (const float*)d_in[9];
  const float* b4 = (const float*)d_in[10];
  float* out = (float*)d_out;

  char* ws = (char*)d_ws;
  size_t off = 0;
  auto alloc = [&](size_t bytes) {
    size_t p = off;
    off = (off + bytes + 255) & ~(size_t)255;
    return p;
  };
  float* ns = (float*)(ws + alloc((size_t)NN * 4));
  float* nd = (float*)(ws + alloc((size_t)NN * 4));
  int* row_off = (int*)(ws + alloc((size_t)(NN + 64) * 4));
  int* col = (int*)(ws + alloc((size_t)NE * 4));
  unsigned short* Wt1 = (unsigned short*)(ws + alloc((size_t)128 * 128 * 2));
  unsigned short* Wt2 = (unsigned short*)(ws + alloc((size_t)128 * 128 * 2));
  unsigned short* Wt3 = (unsigned short*)(ws + alloc((size_t)256 * 128 * 2));
  unsigned short* Wt4 = (unsigned short*)(ws + alloc((size_t)64 * 256 * 2));
  unsigned short* B0 = (unsigned short*)(ws + alloc((size_t)NN * 128 * 2));
  unsigned short* B1 = (unsigned short*)(ws + alloc((size_t)NN * 128 * 2));

  int* degO = (int*)B0;
  int* degI = degO + NN;
  int* cursor = degI + NN;
  int* blk = cursor + NN;

  hipMemsetAsync(degO, 0, 2 * (size_t)NN * 4, stream);

  // XCD-pinned degree count: one launch, window = blockIdx&7
  degcnt_xcd_kernel<<<2048, 256, 0, stream>>>(src, dst, degO, degI, NE);
  normi_kernel<<<(NN + 255) / 256, 256, 0, stream>>>(degO, degI, ns, nd, NN);
  const int nblk = (NN + 1023) / 1024;
  scan1_kernel<<<nblk, 1024, 0, stream>>>(degI, row_off, blk, NN);
  scan2_kernel<<<1, 128, 0, stream>>>(blk, nblk);
  scan3_kernel<<<nblk, 1024, 0, stream>>>(row_off, blk, cursor, NN, NE);

  // XCD-pinned scatter: one launch
  scatter_xcd_kernel<<<2048, 256, 0, stream>>>(src, dst, cursor, col, NE);

  wconv_all_kernel<<<320, 256, 0, stream>>>(W1, Wt1, W2, Wt2, W3, Wt3, W4, Wt4);

  const int nGemmBlk = (NN + 63) / 64;
  const int aggBlocks = (NN * 64 + 255) / 256;

  prescale_kernel<<<(NN * 16 + 255) / 256, 256, 0, stream>>>(feat, ns, B0);
  agg_bf16_kernel<<<aggBlocks, 256, 0, stream>>>(B0, col, row_off, nd, B1, NN);
  gemm_mfma_kernel<<<nGemmBlk, 256, 0, stream>>>(B1, Wt1, b1, ns, B0, NN);
  agg_bf16_kernel<<<aggBlocks, 256, 0, stream>>>(B0, col, row_off, nd, B1, NN);
  gemm_mfma_kernel<<<nGemmBlk, 256, 0, stream>>>(B1, Wt2, b2, nullptr, B0, NN);
  mlp_mfma_kernel<<<nGemmBlk, 256, 0, stream>>>(B0, Wt3, b3, Wt4, b4, out, NN);
}